// Round 1
// 245.026 us; speedup vs baseline: 1.3657x; 1.3657x over previous
//
#include <hip/hip_runtime.h>

#define NCV 100000
#define NTV 300000
#define NPV 50000
#define DD 128
#define OUTC 10
#define EMV 300000
#define EIV 600000
#define YST 16   // y_c / y_p row stride (floats) -> 64B-aligned rows

// ---------------- weight folding (wave-per-output, shuffle reduce) ----------------
// T1 = Wn10@Wout, T2 = Wn12@Wout, T3 = 0.5*(Wr10+Wr12)@Wout  (each 128x10)
__global__ __launch_bounds__(256) void prep_T_w(
    const float* __restrict__ Wn10, const float* __restrict__ Wn12,
    const float* __restrict__ Wr10, const float* __restrict__ Wr12,
    const float* __restrict__ Wout, float* __restrict__ T) {
  int gw = (blockIdx.x * 256 + threadIdx.x) >> 6;
  int lane = threadIdx.x & 63;
  if (gw >= 3 * 1280) return;
  int mat = gw / 1280, r = gw % 1280, n = r / 10, o = r % 10;
  float s = 0.f;
  #pragma unroll
  for (int mi = 0; mi < 2; ++mi) {
    int m = lane + mi * 64;
    float w;
    if (mat == 0) w = Wn10[n * 128 + m];
    else if (mat == 1) w = Wn12[n * 128 + m];
    else w = 0.5f * (Wr10[n * 128 + m] + Wr12[n * 128 + m]);
    s += w * Wout[m * 10 + o];
  }
  #pragma unroll
  for (int d = 32; d; d >>= 1) s += __shfl_xor(s, d);
  if (lane == 0) T[gw] = s;
}

// Q1=Wn01@T1 Q2=Wr01@T1 Q3=Wn03@T2 Q4=Wr03@T2 Q5=Wn00@T3 Q6=Wn02@T3 Q7=(Wr00+Wr02)@T3
__global__ __launch_bounds__(256) void prep_Q_w(
    const float* __restrict__ Wn01, const float* __restrict__ Wr01,
    const float* __restrict__ Wn03, const float* __restrict__ Wr03,
    const float* __restrict__ Wn00, const float* __restrict__ Wn02,
    const float* __restrict__ Wr00, const float* __restrict__ Wr02,
    const float* __restrict__ T, float* __restrict__ Q) {
  int gw = (blockIdx.x * 256 + threadIdx.x) >> 6;
  int lane = threadIdx.x & 63;
  if (gw >= 7 * 1280) return;
  int q = gw / 1280, r = gw % 1280, k = r / 10, o = r % 10;
  const float* T1 = T, *T2 = T + 1280, *T3 = T + 2560;
  float s = 0.f;
  #pragma unroll
  for (int ni = 0; ni < 2; ++ni) {
    int n = lane + ni * 64;
    float w, t;
    switch (q) {
      case 0: w = Wn01[k * 128 + n]; t = T1[n * 10 + o]; break;
      case 1: w = Wr01[k * 128 + n]; t = T1[n * 10 + o]; break;
      case 2: w = Wn03[k * 128 + n]; t = T2[n * 10 + o]; break;
      case 3: w = Wr03[k * 128 + n]; t = T2[n * 10 + o]; break;
      case 4: w = Wn00[k * 128 + n]; t = T3[n * 10 + o]; break;
      case 5: w = Wn02[k * 128 + n]; t = T3[n * 10 + o]; break;
      default: w = Wr00[k * 128 + n] + Wr02[k * 128 + n]; t = T3[n * 10 + o]; break;
    }
    s += w * t;
  }
  #pragma unroll
  for (int d = 32; d; d >>= 1) s += __shfl_xor(s, d);
  if (lane == 0) Q[gw] = s;
}

// Final 45x10 coefficient table B (rows: 0..16 B_c | 17..33 B_p | 34..41 B_t |
// 42 u_c | 43 u_p | 44 k). Uniform outer 0.5; bout added to row 44.
__global__ __launch_bounds__(256) void prep_B_w(
    const float* __restrict__ Wcol, const float* __restrict__ bcol,
    const float* __restrict__ b_lin, const float* __restrict__ Wout,
    const float* __restrict__ bout, const float* __restrict__ T,
    const float* __restrict__ Q, float* __restrict__ B) {
  int gw = (blockIdx.x * 256 + threadIdx.x) >> 6;
  int lane = threadIdx.x & 63;
  if (gw >= 450) return;
  int r = gw / 10, o = gw % 10;
  const float* WcC = Wcol, *WcT = Wcol + 128, *WcP = Wcol + 256;
  const float* bC = bcol, *bT = bcol + 128, *bP = bcol + 256;
  const float* Q1 = Q, *Q2 = Q + 1280, *Q3 = Q + 2560, *Q4 = Q + 3840;
  const float* Q5 = Q + 5120, *Q6 = Q + 6400, *Q7 = Q + 7680;
  const float* T1 = T, *T2 = T + 1280, *T3 = T + 2560;
  const float* b00 = b_lin, *b01 = b_lin + 128, *b02 = b_lin + 256, *b03 = b_lin + 384;
  const float* b10 = b_lin + 512, *b12 = b_lin + 768;
  float s = 0.f;
  if (r < 8) {
    if (lane < 16) s = WcT[r * 16 + lane] * Q1[(r * 16 + lane) * 10 + o];
  } else if (r < 16) {
    int j = r - 8;
    if (lane < 16)
      s = WcC[j * 16 + lane] * (Q2[(j * 16 + lane) * 10 + o] + Q5[(j * 16 + lane) * 10 + o]);
  } else if (r == 16) {
    for (int k2 = lane; k2 < 128; k2 += 64) s += bT[k2] * Q1[k2 * 10 + o];
  } else if (r < 25) {
    int j = r - 17;
    if (lane < 16) s = WcT[j * 16 + lane] * Q3[(j * 16 + lane) * 10 + o];
  } else if (r < 33) {
    int j = r - 25;
    if (lane < 16)
      s = WcP[j * 16 + lane] * (Q4[(j * 16 + lane) * 10 + o] + Q6[(j * 16 + lane) * 10 + o]);
  } else if (r == 33) {
    for (int k2 = lane; k2 < 128; k2 += 64) s += bT[k2] * Q3[k2 * 10 + o];
  } else if (r < 42) {
    int j = r - 34;
    if (lane < 16) s = WcT[j * 16 + lane] * Q7[(j * 16 + lane) * 10 + o];
  } else if (r == 42) {
    for (int k2 = lane; k2 < 128; k2 += 64)
      s += bC[k2] * (Q2[k2 * 10 + o] + Q5[k2 * 10 + o]) + b01[k2] * T1[k2 * 10 + o];
  } else if (r == 43) {
    for (int k2 = lane; k2 < 128; k2 += 64)
      s += bP[k2] * (Q4[k2 * 10 + o] + Q6[k2 * 10 + o]) + b03[k2] * T2[k2 * 10 + o];
  } else {
    for (int n = lane; n < 128; n += 64)
      s += (b10[n] + b12[n]) * Wout[n * 10 + o] + bT[n] * Q7[n * 10 + o] +
           (b00[n] + b02[n]) * T3[n * 10 + o];
  }
  #pragma unroll
  for (int d = 32; d; d >>= 1) s += __shfl_xor(s, d);
  if (lane == 0) {
    float v = s * 0.5f;
    if (r == 44) v += bout[o];
    B[gw] = v;
  }
}

// ---------------- build per-destination linked lists (1 atomicExch per edge per list) ----
// head_c  : list of makes-edges grouped by customer (src)
// head_tm : list of makes-edges grouped by transaction (dst)
// head_p  : list of in-edges grouped by product (src)
// head_ti : list of in-edges grouped by transaction (dst)
__global__ __launch_bounds__(256) void build_lists(
    const int* __restrict__ ems, const int* __restrict__ emd,
    const int* __restrict__ eis, const int* __restrict__ eid,
    int* __restrict__ head_c, int* __restrict__ head_tm,
    int* __restrict__ head_p, int* __restrict__ head_ti,
    int* __restrict__ nxt_mc, int* __restrict__ nxt_mt,
    int* __restrict__ nxt_ip, int* __restrict__ nxt_it) {
  int e = blockIdx.x * 256 + threadIdx.x;
  if (e < EMV) {
    int c = ems[e], t = emd[e];
    nxt_mc[e] = atomicExch(&head_c[c], e);
    nxt_mt[e] = atomicExch(&head_tm[t], e);
  }
  if (e < EIV) {
    int p = eis[e], t = eid[e];
    nxt_ip[e] = atomicExch(&head_p[p], e);
    nxt_it[e] = atomicExch(&head_ti[t], e);
  }
}

// ---------------- gather + finalize y for customers and products -------------------
// Per node: walk its edge list, accumulate x_t rows (mean), then project through B.
// z = [g·x̄_t, x_own, g] -> y = z @ B_side (10 floats)
__global__ __launch_bounds__(256) void gather_y(
    const float* __restrict__ xt,
    const int* __restrict__ emd, const int* __restrict__ eid,
    const int* __restrict__ head_c, const int* __restrict__ head_p,
    const int* __restrict__ nxt_mc, const int* __restrict__ nxt_ip,
    const float* __restrict__ xc, const float* __restrict__ xp,
    const float* __restrict__ B,
    float* __restrict__ y_c, float* __restrict__ y_p) {
  __shared__ float sB[340];   // rows 0..33 of B
  int tid = threadIdx.x;
  for (int i = tid; i < 340; i += 256) sB[i] = B[i];
  __syncthreads();
  int i = blockIdx.x * 256 + tid;
  if (i >= NCV + NPV) return;
  bool isC = i < NCV;
  int idx = isC ? i : i - NCV;
  const int* dstA = isC ? emd : eid;
  const int* nxt = isC ? nxt_mc : nxt_ip;
  int e = isC ? head_c[idx] : head_p[idx];

  float acc[8] = {0.f, 0.f, 0.f, 0.f, 0.f, 0.f, 0.f, 0.f};
  float cnt = 0.f;
  while (e >= 0) {
    const float4* xr = (const float4*)(xt + (size_t)dstA[e] * 8);
    float4 u = xr[0], v = xr[1];
    acc[0] += u.x; acc[1] += u.y; acc[2] += u.z; acc[3] += u.w;
    acc[4] += v.x; acc[5] += v.y; acc[6] += v.z; acc[7] += v.w;
    cnt += 1.f;
    e = nxt[e];
  }

  const float* xo = (isC ? xc : xp) + (size_t)idx * 8;
  const float* Bs = sB + (isC ? 0 : 170);
  float g = cnt > 0.f ? 1.f : 0.f;
  float inv = g / fmaxf(cnt, 1.f);
  float lg[OUTC];
  #pragma unroll
  for (int o = 0; o < OUTC; ++o) lg[o] = g * Bs[16 * 10 + o];
  #pragma unroll
  for (int r = 0; r < 8; ++r) {
    float zb = acc[r] * inv;
    float zo = xo[r];
    #pragma unroll
    for (int o = 0; o < OUTC; ++o)
      lg[o] += zb * Bs[r * 10 + o] + zo * Bs[(8 + r) * 10 + o];
  }
  float* y = (isC ? y_c : y_p) + (size_t)idx * YST;
  #pragma unroll
  for (int o = 0; o < OUTC; ++o) y[o] = lg[o];
}

// ---------------- gather y into each transaction + final combine + softmax ----------
__global__ __launch_bounds__(256) void gather_t(
    const float* __restrict__ y_c, const float* __restrict__ y_p,
    const float* __restrict__ xt,
    const int* __restrict__ ems, const int* __restrict__ eis,
    const int* __restrict__ head_tm, const int* __restrict__ head_ti,
    const int* __restrict__ nxt_mt, const int* __restrict__ nxt_it,
    const float* __restrict__ B, float* __restrict__ out) {
  __shared__ float sB[110];   // rows 34..44 of B
  int tid = threadIdx.x;
  for (int i = tid; i < 110; i += 256) sB[i] = B[340 + i];
  __syncthreads();
  int t = blockIdx.x * 256 + tid;
  if (t >= NTV) return;

  float sc[OUTC] = {0.f, 0.f, 0.f, 0.f, 0.f, 0.f, 0.f, 0.f, 0.f, 0.f};
  float sp[OUTC] = {0.f, 0.f, 0.f, 0.f, 0.f, 0.f, 0.f, 0.f, 0.f, 0.f};
  float dc = 0.f, dp = 0.f;
  for (int e = head_tm[t]; e >= 0; e = nxt_mt[e]) {
    const float* yr = y_c + (size_t)ems[e] * YST;
    float4 u = *(const float4*)yr;
    float4 v = *(const float4*)(yr + 4);
    float2 w = *(const float2*)(yr + 8);
    sc[0] += u.x; sc[1] += u.y; sc[2] += u.z; sc[3] += u.w;
    sc[4] += v.x; sc[5] += v.y; sc[6] += v.z; sc[7] += v.w;
    sc[8] += w.x; sc[9] += w.y;
    dc += 1.f;
  }
  for (int e = head_ti[t]; e >= 0; e = nxt_it[e]) {
    const float* yr = y_p + (size_t)eis[e] * YST;
    float4 u = *(const float4*)yr;
    float4 v = *(const float4*)(yr + 4);
    float2 w = *(const float2*)(yr + 8);
    sp[0] += u.x; sp[1] += u.y; sp[2] += u.z; sp[3] += u.w;
    sp[4] += v.x; sp[5] += v.y; sp[6] += v.z; sp[7] += v.w;
    sp[8] += w.x; sp[9] += w.y;
    dp += 1.f;
  }

  float Gc = dc > 0.f ? 1.f : 0.f, Gp = dp > 0.f ? 1.f : 0.f;
  float ivc = 1.f / fmaxf(dc, 1.f), ivp = 1.f / fmaxf(dp, 1.f);

  const float4* xp4 = (const float4*)(xt + (size_t)t * 8);
  float4 xa = xp4[0], xb = xp4[1];
  float xv[8] = {xa.x, xa.y, xa.z, xa.w, xb.x, xb.y, xb.z, xb.w};

  float lg[OUTC];
  #pragma unroll
  for (int o = 0; o < OUTC; ++o)
    lg[o] = sc[o] * ivc + sp[o] * ivp +
            Gc * sB[80 + o] + Gp * sB[90 + o] + sB[100 + o];
  #pragma unroll
  for (int r = 0; r < 8; ++r) {
    float xr = xv[r];
    #pragma unroll
    for (int o = 0; o < OUTC; ++o) lg[o] += xr * sB[r * 10 + o];
  }

  float m = lg[0];
  #pragma unroll
  for (int o = 1; o < OUTC; ++o) m = fmaxf(m, lg[o]);
  float s = 0.f;
  #pragma unroll
  for (int o = 0; o < OUTC; ++o) { lg[o] = __expf(lg[o] - m); s += lg[o]; }
  float invs = 1.0f / s;
  float* op = &out[(size_t)t * OUTC];
  #pragma unroll
  for (int o = 0; o < 5; ++o) {
    float2 p2; p2.x = lg[2 * o] * invs; p2.y = lg[2 * o + 1] * invs;
    *(float2*)&op[2 * o] = p2;
  }
}

extern "C" void kernel_launch(void* const* d_in, const int* in_sizes, int n_in,
                              void* d_out, int out_size, void* d_ws, size_t ws_size,
                              hipStream_t stream) {
  const float* x_c   = (const float*)d_in[0];
  const float* x_t   = (const float*)d_in[1];
  const float* x_p   = (const float*)d_in[2];
  const float* W_col = (const float*)d_in[3];
  const float* b_col = (const float*)d_in[4];
  const float* Wn    = (const float*)d_in[5];
  const float* Wr    = (const float*)d_in[6];
  const float* b_lin = (const float*)d_in[7];
  const float* W_out = (const float*)d_in[8];
  const float* b_out = (const float*)d_in[9];
  const int* e_m_src = (const int*)d_in[10];
  const int* e_m_dst = (const int*)d_in[11];
  const int* e_i_src = (const int*)d_in[12];
  const int* e_i_dst = (const int*)d_in[13];
  float* out = (float*)d_out;

  // ---- workspace carve-out (~23 MB; ws_size = 256 MiB) ----
  size_t cursor = 0;
  char* base = (char*)d_ws;
  auto alloc = [&](size_t bytes) {
    void* p = base + cursor;
    cursor += (bytes + 255) & ~(size_t)255;
    return p;
  };
  float* y_c  = (float*)alloc((size_t)NCV * YST * 4);              // 6.4 MB
  float* y_p  = (float*)alloc((size_t)NPV * YST * 4);              // 3.2 MB
  int* heads  = (int*)alloc((size_t)(NCV + NPV + 2 * NTV) * 4);    // 3.0 MB
  int* head_c  = heads;
  int* head_p  = heads + NCV;
  int* head_tm = heads + NCV + NPV;
  int* head_ti = heads + NCV + NPV + NTV;
  int* nxt_mc = (int*)alloc((size_t)EMV * 4);                      // 1.2 MB
  int* nxt_mt = (int*)alloc((size_t)EMV * 4);                      // 1.2 MB
  int* nxt_ip = (int*)alloc((size_t)EIV * 4);                      // 2.4 MB
  int* nxt_it = (int*)alloc((size_t)EIV * 4);                      // 2.4 MB
  float* T    = (float*)alloc(3 * 1280 * 4);
  float* Q    = (float*)alloc(7 * 1280 * 4);
  float* B    = (float*)alloc(450 * 4);

  const float* Wn_l[2][4]; const float* Wr_l[2][4];
  for (int l = 0; l < 2; ++l)
    for (int r = 0; r < 4; ++r) {
      Wn_l[l][r] = Wn + (size_t)(l * 4 + r) * DD * DD;
      Wr_l[l][r] = Wr + (size_t)(l * 4 + r) * DD * DD;
    }

  // ---- init list heads to -1 (0xFFFFFFFF) ----
  hipMemsetAsync(heads, 0xFF, (size_t)(NCV + NPV + 2 * NTV) * 4, stream);

  // ---- weight folding ----
  prep_T_w<<<(3 * 1280 * 64 + 255) / 256, 256, 0, stream>>>(
      Wn_l[1][0], Wn_l[1][2], Wr_l[1][0], Wr_l[1][2], W_out, T);
  prep_Q_w<<<(7 * 1280 * 64 + 255) / 256, 256, 0, stream>>>(
      Wn_l[0][1], Wr_l[0][1], Wn_l[0][3], Wr_l[0][3],
      Wn_l[0][0], Wn_l[0][2], Wr_l[0][0], Wr_l[0][2], T, Q);
  prep_B_w<<<(450 * 64 + 255) / 256, 256, 0, stream>>>(
      W_col, b_col, b_lin, W_out, b_out, T, Q, B);

  // ---- build per-destination edge lists (replaces all f32 atomic scatter) ----
  build_lists<<<(EIV + 255) / 256, 256, 0, stream>>>(
      e_m_src, e_m_dst, e_i_src, e_i_dst,
      head_c, head_tm, head_p, head_ti,
      nxt_mc, nxt_mt, nxt_ip, nxt_it);

  // ---- gather x_t into customers/products + project through B (was passA+finalize_y) ----
  gather_y<<<(NCV + NPV + 255) / 256, 256, 0, stream>>>(
      x_t, e_m_dst, e_i_dst, head_c, head_p, nxt_mc, nxt_ip,
      x_c, x_p, B, y_c, y_p);

  // ---- gather y into transactions + combine + softmax (was passB+final_t) ----
  gather_t<<<(NTV + 255) / 256, 256, 0, stream>>>(
      y_c, y_p, x_t, e_m_src, e_i_src, head_tm, head_ti,
      nxt_mt, nxt_it, B, out);
}